// Round 3
// baseline (589.576 us; speedup 1.0000x reference)
//
#include <hip/hip_runtime.h>
#include <math.h>

#define CI 12
#define NHID 15
#define NBLK 6144                 // 8*3*16*16 image blocks of 32x32
#define NPIX (NBLK * 1024)

typedef float  f32x4 __attribute__((ext_vector_type(4)));
typedef int    i32x4 __attribute__((ext_vector_type(4)));
typedef short  s16x8 __attribute__((ext_vector_type(8)));

static __device__ __forceinline__ float bperm(float v, int addr4) {
    return __int_as_float(__builtin_amdgcn_ds_bpermute(addr4, __float_as_int(v)));
}
// f32 -> bf16 truncation pack (hot loop; trunc err 2^-8 rel, fine vs thr 2.94)
static __device__ __forceinline__ int bfpack(float lo, float hi) {
    return (int)((__float_as_uint(hi) & 0xFFFF0000u) | (__float_as_uint(lo) >> 16));
}
// f32 -> bf16 RNE (weights, done once)
static __device__ __forceinline__ unsigned bfrne(float x) {
    unsigned u = __float_as_uint(x);
    u += 0x7FFFu + ((u >> 16) & 1u);
    return u >> 16;
}
static __device__ __forceinline__ int bfpack_rne(float lo, float hi) {
    return (int)((bfrne(hi) << 16) | bfrne(lo));
}
static __device__ __forceinline__ float leaky(float x) {
    return fmaxf(x, 0.01f * x);
}

__global__ __launch_bounds__(256, 4) void codec_main(
    const float* __restrict__ x,
    const float* __restrict__ Wh,   // [15][12][12]
    const float* __restrict__ bh,   // [15][12]
    const float* __restrict__ Wo,   // [12]
    const float* __restrict__ bo,   // [1]
    float* __restrict__ out,        // [1 + NPIX]
    float* __restrict__ loss_acc)   // [1] pre-zeroed
{
    __shared__ float tile[36][37];  // 32x32 + 2-halo, +1 col pad
    __shared__ float wsum[4];

    const int n    = blockIdx.x;
    const int tid  = threadIdx.x;   // 0..255
    const int lane = tid & 63;
    const int wv   = tid >> 6;      // wave 0..3
    const int t    = lane & 15;     // pixel-column role / weight-row role
    const int q    = lane >> 4;     // quad 0..3

    // ---- stage image block into LDS (zero halo = per-block zero padding) ----
    {
        const int col = tid & 31;
        const int r0  = tid >> 5;   // 0..7
        #pragma unroll
        for (int i = 0; i < 6; ++i) {
            int idx = tid + i * 256;
            if (idx < 36 * 37) ((float*)tile)[idx] = 0.0f;
        }
        __syncthreads();
        const int bc  = n >> 8;
        const int blk = n & 255;
        const int by  = blk >> 4;
        const int bx  = blk & 15;
        #pragma unroll
        for (int p = 0; p < 4; ++p) {
            const int row = r0 + 8 * p;
            tile[row + 2][col + 2] =
                x[((size_t)bc * 512 + (size_t)(by * 32 + row)) * 512
                  + (size_t)(bx * 32 + col)];
        }
        __syncthreads();
    }

    // ---- preload weight A-frags: A[m=o=t][k=8q+e] = W~[o][k], bias at k=12 ----
    i32x4 wA[NHID];
    i32x4 wHd;
    #pragma unroll
    for (int l = 0; l < NHID; ++l) {
        float g0=0,g1=0,g2=0,g3=0,g4=0,g5=0,g6=0,g7=0;
        if (t < CI) {
            const float* Wl = Wh + l * (CI * CI) + t * CI;
            if (q == 0) {
                float4 u0 = *(const float4*)(Wl);
                float4 u1 = *(const float4*)(Wl + 4);
                g0=u0.x; g1=u0.y; g2=u0.z; g3=u0.w;
                g4=u1.x; g5=u1.y; g6=u1.z; g7=u1.w;
            } else if (q == 1) {
                float4 u = *(const float4*)(Wl + 8);
                g0=u.x; g1=u.y; g2=u.z; g3=u.w;
                g4 = bh[l * CI + t];       // k=12 -> bias
            }
        }
        wA[l] = (i32x4){ bfpack_rne(g0,g1), bfpack_rne(g2,g3),
                         bfpack_rne(g4,g5), bfpack_rne(g6,g7) };
    }
    {
        float g0=0,g1=0,g2=0,g3=0,g4=0,g5=0,g6=0,g7=0;
        if (t == 0) {
            if (q == 0) {
                float4 u0 = *(const float4*)(Wo);
                float4 u1 = *(const float4*)(Wo + 4);
                g0=u0.x; g1=u0.y; g2=u0.z; g3=u0.w;
                g4=u1.x; g5=u1.y; g6=u1.z; g7=u1.w;
            } else if (q == 1) {
                float4 u = *(const float4*)(Wo + 8);
                g0=u.x; g1=u.y; g2=u.z; g3=u.w;
                g4 = bo[0];                // k=12 -> bias
            }
        }
        wHd = (i32x4){ bfpack_rne(g0,g1), bfpack_rne(g2,g3),
                       bfpack_rne(g4,g5), bfpack_rne(g6,g7) };
    }

    // shuffle addresses for the C->B transform (bytes, lane*4)
    const int sA4 = ((t) + ((q == 1) ? 32 : 0)) * 4;  // e=0..3: q0<-q'0, q1<-q'2
    const int sB4 = (t + 16) * 4;                     // e=4..7: q0<-q'1
    const bool q_is_1 = (q == 1);

    // ---- 16 pixel-groups per wave: group g -> row y=g>>1, half xh=g&1 ----
    float d2loc = 0.0f;
    const f32x4 zero4 = {0.0f, 0.0f, 0.0f, 0.0f};
    for (int g = wv * 16; g < wv * 16 + 16; ++g) {
        const int y  = g >> 1;
        const int xh = g & 1;
        const int px = xh * 16 + t;
        const int yy = y + 2, xx = px + 2;

        // build initial B-frag: B[k=feat][n=pixel t], k=12 slot = 1.0
        float f0, f1, f2, f3, f4, f5, f6, f7;
        if (q == 0) {
            f0 = tile[yy-2][xx-2]; f1 = tile[yy-2][xx-1];
            f2 = tile[yy-2][xx  ]; f3 = tile[yy-2][xx+1];
            f4 = tile[yy-2][xx+2]; f5 = tile[yy-1][xx-2];
            f6 = tile[yy-1][xx-1]; f7 = tile[yy-1][xx  ];
        } else if (q == 1) {
            f0 = tile[yy-1][xx+1]; f1 = tile[yy-1][xx+2];
            f2 = tile[yy  ][xx-2]; f3 = tile[yy  ][xx-1];
            f4 = 1.0f; f5 = 0.0f; f6 = 0.0f; f7 = 0.0f;
        } else {
            f0=f1=f2=f3=f4=f5=f6=f7 = 0.0f;   // k>=16: multiplied by 0 weights
        }
        i32x4 B = (i32x4){ bfpack(f0,f1), bfpack(f2,f3),
                           bfpack(f4,f5), bfpack(f6,f7) };

        // 15 hidden layers: D = W~ . H^T  (one MFMA each), then quad-shuffle
        #pragma unroll
        for (int l = 0; l < NHID; ++l) {
            f32x4 acc = __builtin_amdgcn_mfma_f32_16x16x32_bf16(
                __builtin_bit_cast(s16x8, wA[l]),
                __builtin_bit_cast(s16x8, B), zero4, 0, 0, 0);
            const float a0 = leaky(acc[0]);
            const float a1 = leaky(acc[1]);
            const float a2 = leaky(acc[2]);
            const float a3 = leaky(acc[3]);
            // next B: lane(q,e): k=8q+e <- out-channel o=8q+e of pixel t
            float t0 = bperm(a0, sA4);
            float t1 = bperm(a1, sA4);
            float t2 = bperm(a2, sA4);
            float t3 = bperm(a3, sA4);
            float t4 = bperm(a0, sB4);
            float t5 = bperm(a1, sB4);
            float t6 = bperm(a2, sB4);
            float t7 = bperm(a3, sB4);
            t4 = q_is_1 ? 1.0f : t4;           // k=12 bias slot
            B = (i32x4){ bfpack(t0,t1), bfpack(t2,t3),
                         bfpack(t4,t5), bfpack(t6,t7) };
        }

        // head: pred for pixel t lands in lanes 0..15, acc[0]
        f32x4 ah = __builtin_amdgcn_mfma_f32_16x16x32_bf16(
            __builtin_bit_cast(s16x8, wHd),
            __builtin_bit_cast(s16x8, B), zero4, 0, 0, 0);
        if (lane < 16) {
            float pred = fminf(fmaxf(ah[0], -1.0f), 1.0f);
            const float v = tile[yy][xx];      // exact f32 original
            const float delta = fmodf(v - pred + 1.0f, 2.0f) - 1.0f;
            out[1 + (size_t)n * 1024 + (size_t)(y * 32 + px)] = delta;
            d2loc = fmaf(delta, delta, d2loc);
        }
    }

    // ---- loss reduction ----
    #pragma unroll
    for (int off = 32; off > 0; off >>= 1) d2loc += __shfl_down(d2loc, off, 64);
    if (lane == 0) wsum[wv] = d2loc;
    __syncthreads();
    if (tid == 0) atomicAdd(loss_acc, wsum[0] + wsum[1] + wsum[2] + wsum[3]);
}

__global__ void codec_loss(const float* __restrict__ acc, float* __restrict__ out)
{
    out[0] = 255.0f * sqrtf(acc[0] / (float)NPIX);
}

extern "C" void kernel_launch(void* const* d_in, const int* in_sizes, int n_in,
                              void* d_out, int out_size, void* d_ws, size_t ws_size,
                              hipStream_t stream)
{
    const float* x  = (const float*)d_in[0];
    const float* Wh = (const float*)d_in[1];
    const float* bh = (const float*)d_in[2];
    const float* Wo = (const float*)d_in[3];
    const float* bo = (const float*)d_in[4];
    float* out = (float*)d_out;
    float* acc = (float*)d_ws;

    hipMemsetAsync(acc, 0, sizeof(float), stream);   // graph-capture safe
    codec_main<<<NBLK, 256, 0, stream>>>(x, Wh, bh, Wo, bo, out, acc);
    codec_loss<<<1, 1, 0, stream>>>(acc, out);
}

// Round 4
// 247.024 us; speedup vs baseline: 2.3867x; 2.3867x over previous
//
#include <hip/hip_runtime.h>
#include <math.h>

#define CI 12
#define NHID 15
#define NBLK 6144                 // 8*3*16*16 image blocks of 32x32
#define NPIX (NBLK * 1024)

typedef float  f32x4 __attribute__((ext_vector_type(4)));
typedef int    i32x4 __attribute__((ext_vector_type(4)));
typedef short  s16x8 __attribute__((ext_vector_type(8)));

// f32 -> bf16 trunc pack via byte-perm: dst = hi16(hi) << 16 | hi16(lo)
static __device__ __forceinline__ int bfpack(float lo, float hi) {
    return (int)__builtin_amdgcn_perm(__float_as_uint(hi), __float_as_uint(lo),
                                      0x07060302u);
}
// f32 -> bf16 RNE (weights, cold path)
static __device__ __forceinline__ unsigned bfrne(float x) {
    unsigned u = __float_as_uint(x);
    u += 0x7FFFu + ((u >> 16) & 1u);
    return u >> 16;
}
static __device__ __forceinline__ int bfpack_rne(float lo, float hi) {
    return (int)((bfrne(hi) << 16) | bfrne(lo));
}
static __device__ __forceinline__ float leaky(float x) {
    return fmaxf(x, 0.01f * x);
}
static __device__ __forceinline__ f32x4 mfma16(i32x4 a, i32x4 b, f32x4 c) {
    return __builtin_amdgcn_mfma_f32_16x16x32_bf16(
        __builtin_bit_cast(s16x8, a), __builtin_bit_cast(s16x8, b), c, 0, 0, 0);
}

// Sparse-K layout: channel c=4q+r lives at k-slot 8q+r (q=0..2); bias at k=4;
// all other k-slots have zero weights -> MFMA C-layout output (lane 16q+t holds
// channels 4q..4q+3 of pixel t) IS already the next B-frag, no cross-lane moves.
__global__ __launch_bounds__(256, 4) void codec_main(
    const float* __restrict__ x,
    const float* __restrict__ Wh,   // [15][12][12]
    const float* __restrict__ bh,   // [15][12]
    const float* __restrict__ Wo,   // [12]
    const float* __restrict__ bo,   // [1]
    float* __restrict__ out,        // [1 + NPIX]
    float* __restrict__ loss_acc)   // [1] pre-zeroed
{
    __shared__ float tile[36 * 37]; // 32x32 + 2-halo, +1 col pad
    __shared__ float stage[4][256]; // per-wave delta staging for coalesced store
    __shared__ float wsum[4];

    const int n    = blockIdx.x;
    const int tid  = threadIdx.x;   // 0..255
    const int lane = tid & 63;
    const int wv   = tid >> 6;      // wave 0..3
    const int t    = lane & 15;     // pixel role / weight-row role
    const int q    = lane >> 4;     // quad 0..3

    // ---- stage image block into LDS (zero halo = per-block zero padding) ----
    {
        const int col = tid & 31;
        const int r0  = tid >> 5;   // 0..7
        #pragma unroll
        for (int i = 0; i < 6; ++i) {
            int idx = tid + i * 256;
            if (idx < 36 * 37) tile[idx] = 0.0f;
        }
        __syncthreads();
        const int bc  = n >> 8;
        const int blk = n & 255;
        const int by  = blk >> 4;
        const int bx  = blk & 15;
        #pragma unroll
        for (int p = 0; p < 4; ++p) {
            const int row = r0 + 8 * p;
            tile[(row + 2) * 37 + col + 2] =
                x[((size_t)bc * 512 + (size_t)(by * 32 + row)) * 512
                  + (size_t)(bx * 32 + col)];
        }
        __syncthreads();
    }

    // ---- weight A-frags: lane 16q+t holds A[m=t][k=8q+j], j=0..7 ----
    // j=0..3 <- W[t][4q+j]; (q==0,j==4) <- bias; else 0
    i32x4 wA[NHID];
    i32x4 wHd;
    const bool wok = (t < CI) && (q < 3);
    #pragma unroll
    for (int l = 0; l < NHID; ++l) {
        float4 w = {0.f, 0.f, 0.f, 0.f};
        float  b = 0.f;
        if (wok) w = *(const float4*)(Wh + l * (CI * CI) + t * CI + 4 * q);
        if (wok && q == 0) b = bh[l * CI + t];
        wA[l] = (i32x4){ bfpack_rne(w.x, w.y), bfpack_rne(w.z, w.w),
                         bfpack_rne(b, 0.f), 0 };
    }
    {
        float4 w = {0.f, 0.f, 0.f, 0.f};
        float  b = 0.f;
        if (t == 0 && q < 3) w = *(const float4*)(Wo + 4 * q);
        if (t == 0 && q == 0) b = bo[0];
        wHd = (i32x4){ bfpack_rne(w.x, w.y), bfpack_rne(w.z, w.w),
                       bfpack_rne(b, 0.f), 0 };
    }

    // ---- per-lane feature LDS offsets: feature c=4q+r at (dy,dx); off=dy*37+dx
    // packed as signed bytes by q: r0:{-76,-72,-36,0} r1:{-75,-39,-35,0}
    //                              r2:{-74,-38,-2,0}  r3:{-73,-37,-1,0}
    const int sh8  = q * 8;
    const int off0 = (int)(signed char)((0x00DCB8B4u >> sh8) & 0xFFu);
    const int off1 = (int)(signed char)((0x00DDD9B5u >> sh8) & 0xFFu);
    const int off2 = (int)(signed char)((0x00FEDAB6u >> sh8) & 0xFFu);
    const int off3 = (int)(signed char)((0x00FFDBB7u >> sh8) & 0xFFu);

    const int biasreg = (q == 0) ? 0x00003F80 : 0;   // k=4 slot = bf16(1.0)
    const f32x4 zero4 = {0.f, 0.f, 0.f, 0.f};

    float d2 = 0.0f;
    for (int gi = 0; gi < 16; ++gi) {
        const int g   = wv * 16 + gi;
        const int y   = g >> 1;              // image-block row 0..31
        const int px  = (g & 1) * 16 + t;    // image-block col 0..31
        const int pix = (y + 2) * 37 + (px + 2);

        // initial B: k=8q+r <- feature 4q+r of pixel t (quad 3 reads own pixel,
        // harmless: weight rows k>=24 are zero)
        int B0 = bfpack(tile[pix + off0], tile[pix + off1]);
        int B1 = bfpack(tile[pix + off2], tile[pix + off3]);

        #pragma unroll
        for (int l = 0; l < NHID; ++l) {
            f32x4 a = mfma16(wA[l], (i32x4){B0, B1, biasreg, 0}, zero4);
            B0 = bfpack(leaky(a[0]), leaky(a[1]));
            B1 = bfpack(leaky(a[2]), leaky(a[3]));
        }
        f32x4 ah = mfma16(wHd, (i32x4){B0, B1, biasreg, 0}, zero4);

        if (lane < 16) {                     // row 0 of D = prediction
            const float pred  = fminf(fmaxf(ah[0], -1.0f), 1.0f);
            const float v     = tile[pix];   // exact f32 original
            const float u     = v - pred + 1.0f;
            const float delta = u - ((u < 2.0f) ? 1.0f : 3.0f); // == fmod(u,2)-1
            stage[wv][(gi >> 1) * 32 + px] = delta;
            d2 = fmaf(delta, delta, d2);
        }
    }

    // ---- coalesced delta store: wave's 256 floats = rows [8wv, 8wv+8) ----
    float* outp = out + 1 + (size_t)n * 1024 + wv * 256;
    #pragma unroll
    for (int j = 0; j < 4; ++j)
        outp[j * 64 + lane] = stage[wv][j * 64 + lane];

    // ---- loss reduction (d2 nonzero only in lanes 0..15) ----
    #pragma unroll
    for (int off = 8; off > 0; off >>= 1) d2 += __shfl_down(d2, off, 64);
    if (lane == 0) wsum[wv] = d2;
    __syncthreads();
    if (tid == 0) atomicAdd(loss_acc, wsum[0] + wsum[1] + wsum[2] + wsum[3]);
}

__global__ void codec_loss(const float* __restrict__ acc, float* __restrict__ out)
{
    out[0] = 255.0f * sqrtf(acc[0] / (float)NPIX);
}

extern "C" void kernel_launch(void* const* d_in, const int* in_sizes, int n_in,
                              void* d_out, int out_size, void* d_ws, size_t ws_size,
                              hipStream_t stream)
{
    const float* x  = (const float*)d_in[0];
    const float* Wh = (const float*)d_in[1];
    const float* bh = (const float*)d_in[2];
    const float* Wo = (const float*)d_in[3];
    const float* bo = (const float*)d_in[4];
    float* out = (float*)d_out;
    float* acc = (float*)d_ws;

    hipMemsetAsync(acc, 0, sizeof(float), stream);   // graph-capture safe
    codec_main<<<NBLK, 256, 0, stream>>>(x, Wh, bh, Wo, bo, out, acc);
    codec_loss<<<1, 1, 0, stream>>>(acc, out);
}